// Round 2
// baseline (978.469 us; speedup 1.0000x reference)
//
#include <hip/hip_runtime.h>

typedef float f32x4 __attribute__((ext_vector_type(4)));
typedef short short8 __attribute__((ext_vector_type(8)));

// Problem constants
#define B_    32
#define NV_   2048
#define NS_   512
#define L_    64
#define FEAT_ 1024
#define SEM_  512
#define HID_  512
#define ATT_  512
#define DM_   512

__device__ __forceinline__ unsigned int f2bf_pk(float lo, float hi) {
  unsigned int ul = (__float_as_uint(lo) + 0x8000u) >> 16;
  unsigned int uh = (__float_as_uint(hi) + 0x8000u) & 0xffff0000u;
  return uh | ul;
}

__device__ __forceinline__ unsigned short f2bf(float f) {
  return (unsigned short)((__float_as_uint(f) + 0x8000u) >> 16);
}

__device__ __forceinline__ float fast_tanh(float x) {
  float e = __expf(2.f * x);
  return 1.f - 2.f * __builtin_amdgcn_rcpf(e + 1.f);
}

// async global->LDS, 16 B per lane. lds ptr must be wave-uniform; lane i lands at lds + i*16.
__device__ __forceinline__ void gll16(const void* g, void* l) {
  __builtin_amdgcn_global_load_lds(
      (const __attribute__((address_space(1))) unsigned int*)g,
      (__attribute__((address_space(3))) unsigned int*)l, 16, 0, 0);
}

// ---------------- K0a: patient mean ----------------
__global__ __launch_bounds__(256) void k_pmean(const float* __restrict__ pat,
                                               float* __restrict__ pm) {
  int b = blockIdx.x, t = threadIdx.x;
  for (int d = t; d < DM_; d += 256) {
    float s = 0.f;
    for (int l = 0; l < L_; ++l) s += pat[(b * L_ + l) * DM_ + d];
    pm[b * DM_ + d] = s * (1.f / 64.f);
  }
}

// ---------------- K0b: qpv/qps ----------------
__global__ __launch_bounds__(256) void k_qp(const float* __restrict__ query,
                                            const float* __restrict__ pm,
                                            const float* __restrict__ W1v,
                                            const float* __restrict__ W1s,
                                            const float* __restrict__ W3,
                                            const float* __restrict__ b3,
                                            float* __restrict__ qpv,
                                            float* __restrict__ qps) {
  int idx = blockIdx.x * 256 + threadIdx.x;
  int b = idx >> 9, a = idx & 511;
  float pi = b3[a];
  for (int d = 0; d < DM_; ++d) pi += pm[b * DM_ + d] * W3[d * ATT_ + a];
  float qv = 0.f, qs = 0.f;
  for (int h = 0; h < HID_; ++h) {
    float q = query[b * HID_ + h];
    qv += q * W1v[h * ATT_ + a];
    qs += q * W1s[h * ATT_ + a];
  }
  qpv[idx] = qv + pi;
  qps[idx] = qs + pi;
}

// ---------------- K0c: swizzle W2 (K x 512 fp32) -> bf16 B-fragment order ----------
// element out index = (kc*32 + cb)*512 + q*128 + n*8 + j ; k=kc*32+q*8+j, col=cb*16+n
__global__ __launch_bounds__(256) void k_swz(const float* __restrict__ W2,
                                             unsigned short* __restrict__ out,
                                             int total) {
  int idx = blockIdx.x * 256 + threadIdx.x;
  if (idx >= total) return;
  int k = idx >> 9, c = idx & 511;
  int kc = k >> 5, kr = k & 31, q = kr >> 3, j = kr & 7;
  int cb = c >> 4, n = c & 15;
  out[(kc * 32 + cb) * 512 + q * 128 + n * 8 + j] = f2bf(W2[idx]);
}

// ---------------- K0d: X fp32 row-major -> bf16 swizzled to A-tile LDS image -------
// per (rt,kc) 8KB block layout [rb<8][q<4][m<16][j<8]; row=rt*128+rb*16+m, k=kc*32+q*8+j
__global__ __launch_bounds__(256) void k_cvtA(const float* __restrict__ X,
                                              unsigned short* __restrict__ out,
                                              int K) {
  const int rt = blockIdx.x, kc = blockIdx.y, nkc = K >> 5;
  const int t = threadIdx.x;
  uint4* dst = (uint4*)(out + ((size_t)rt * nkc + kc) * 4096);
#pragma unroll
  for (int p = 0; p < 2; ++p) {
    int c = p * 256 + t;
    int rb = c >> 6, q = (c >> 4) & 3, m = c & 15;
    int row = rt * 128 + rb * 16 + m;
    const float4* src = (const float4*)(X + (size_t)row * K + kc * 32 + q * 8);
    float4 v0 = src[0], v1 = src[1];
    uint4 o;
    o.x = f2bf_pk(v0.x, v0.y);
    o.y = f2bf_pk(v0.z, v0.w);
    o.z = f2bf_pk(v1.x, v1.y);
    o.w = f2bf_pk(v1.z, v1.w);
    dst[c] = o;
  }
}

// ---------------- K1: fused score GEMM (bf16 pre-swizzled A and B) ----------------
// grid (4 col-tiles, M/128 row-tiles). 128x128 tile, BK=32, 4 waves 2x2, 4x4 acc/wave.
__global__ __launch_bounds__(256) void k_scores_bf16(const unsigned short* __restrict__ Aswz,
                                                     const unsigned short* __restrict__ Wt,
                                                     const float* __restrict__ qp,
                                                     const float* __restrict__ vvec,
                                                     float* __restrict__ score,
                                                     int K, int rows_per_batch) {
  __shared__ __align__(16) unsigned short As[4096];
  __shared__ __align__(16) unsigned short Bs[4096];
  const int t = threadIdx.x;
  const int lane = t & 63;
  const int wave = t >> 6;
  const int wr = wave & 1, wc = wave >> 1;
  const int quad = lane >> 4, l15 = lane & 15;
  const int ct = blockIdx.x;
  const int rt = blockIdx.y;
  const int row0 = rt * 128;
  const int b = row0 / rows_per_batch;
  const int nk = K >> 5;

  char* ldsA = (char*)As + wave * 1024;
  char* ldsB = (char*)Bs + wave * 1024;
  const char* gA = (const char*)(Aswz + (size_t)rt * nk * 4096) + t * 16;
  const char* gB = (const char*)Wt + (size_t)ct * 8192 + t * 16;

  const f32x4 zero = {0.f, 0.f, 0.f, 0.f};
  f32x4 acc[4][4];
#pragma unroll
  for (int a = 0; a < 4; ++a)
#pragma unroll
    for (int bb = 0; bb < 4; ++bb) acc[a][bb] = zero;

  for (int kc = 0; kc < nk; ++kc) {
    __syncthreads();
    gll16(gA, ldsA);
    gll16(gA + 4096, ldsA + 4096);
    gll16(gB, ldsB);
    gll16(gB + 4096, ldsB + 4096);
    gA += 8192;
    gB += 32768;  // (kc*4 + ct) blocks of 8KB
    __syncthreads();
    short8 af[4], bfr[4];
#pragma unroll
    for (int a = 0; a < 4; ++a)
      af[a] = *(const short8*)(As + (wr * 4 + a) * 512 + quad * 128 + l15 * 8);
#pragma unroll
    for (int bb = 0; bb < 4; ++bb)
      bfr[bb] = *(const short8*)(Bs + (wc * 4 + bb) * 512 + quad * 128 + l15 * 8);
#pragma unroll
    for (int a = 0; a < 4; ++a)
#pragma unroll
      for (int bb = 0; bb < 4; ++bb)
        acc[a][bb] = __builtin_amdgcn_mfma_f32_16x16x32_bf16(af[a], bfr[bb], acc[a][bb], 0, 0, 0);
  }

  const int colbase = ct * 128 + wc * 64;
  float qv_[4], vw_[4];
#pragma unroll
  for (int bb = 0; bb < 4; ++bb) {
    int col = colbase + bb * 16 + l15;
    qv_[bb] = qp[b * ATT_ + col];
    vw_[bb] = vvec[col];
  }
#pragma unroll
  for (int a = 0; a < 4; ++a) {
#pragma unroll
    for (int r = 0; r < 4; ++r) {
      float s = 0.f;
#pragma unroll
      for (int bb = 0; bb < 4; ++bb)
        s += fast_tanh(acc[a][bb][r] + qv_[bb]) * vw_[bb];
      s += __shfl_xor(s, 1);
      s += __shfl_xor(s, 2);
      s += __shfl_xor(s, 4);
      s += __shfl_xor(s, 8);
      if (l15 == 0) {
        int row = row0 + wr * 64 + a * 16 + quad * 4 + r;
        atomicAdd(&score[row], s);
      }
    }
  }
}

// ---------------- K1-fallback: round-1 kernel (inline fp32->bf16 staging) ----------
__global__ __launch_bounds__(256) void k_scores_f32(const float* __restrict__ X,
                                                    const unsigned short* __restrict__ Wt,
                                                    const float* __restrict__ qp,
                                                    const float* __restrict__ vvec,
                                                    float* __restrict__ score,
                                                    int K, int rows_per_batch) {
  __shared__ __align__(16) unsigned short As[4096];
  __shared__ __align__(16) unsigned short Bs[4096];
  const int t = threadIdx.x;
  const int lane = t & 63;
  const int wave = t >> 6;
  const int wr = wave & 1, wc = wave >> 1;
  const int quad = lane >> 4, l15 = lane & 15;
  const int row0 = blockIdx.x * 128;
  const int ct = blockIdx.y;
  const int b = row0 / rows_per_batch;

  const int ai_row = t >> 3;
  const int ai_k0 = (t & 7) * 4;
  const int a_q = ai_k0 >> 3;
  const int a_j0 = ai_k0 & 7;

  const f32x4 zero = {0.f, 0.f, 0.f, 0.f};
  f32x4 acc[4][4];
#pragma unroll
  for (int a = 0; a < 4; ++a)
#pragma unroll
    for (int bb = 0; bb < 4; ++bb) acc[a][bb] = zero;

  const int nk = K >> 5;
  for (int kc = 0; kc < nk; ++kc) {
    __syncthreads();
#pragma unroll
    for (int ii = 0; ii < 4; ++ii) {
      int i = ii * 32 + ai_row;
      const float4 v = *(const float4*)(X + (size_t)(row0 + i) * K + kc * 32 + ai_k0);
      uint2 h;
      h.x = f2bf_pk(v.x, v.y);
      h.y = f2bf_pk(v.z, v.w);
      int rb = i >> 4, m = i & 15;
      *(uint2*)(As + rb * 512 + a_q * 128 + m * 8 + a_j0) = h;
    }
    {
      const uint4* src = (const uint4*)(Wt + (size_t)(kc * 32 + ct * 8) * 512);
      uint4* dst = (uint4*)Bs;
      dst[t] = src[t];
      dst[t + 256] = src[t + 256];
    }
    __syncthreads();
    short8 af[4], bfr[4];
#pragma unroll
    for (int a = 0; a < 4; ++a)
      af[a] = *(const short8*)(As + (wr * 4 + a) * 512 + quad * 128 + l15 * 8);
#pragma unroll
    for (int bb = 0; bb < 4; ++bb)
      bfr[bb] = *(const short8*)(Bs + (wc * 4 + bb) * 512 + quad * 128 + l15 * 8);
#pragma unroll
    for (int a = 0; a < 4; ++a)
#pragma unroll
      for (int bb = 0; bb < 4; ++bb)
        acc[a][bb] = __builtin_amdgcn_mfma_f32_16x16x32_bf16(af[a], bfr[bb], acc[a][bb], 0, 0, 0);
  }

  const int colbase = ct * 128 + wc * 64;
  float qv_[4], vw_[4];
#pragma unroll
  for (int bb = 0; bb < 4; ++bb) {
    int col = colbase + bb * 16 + l15;
    qv_[bb] = qp[b * ATT_ + col];
    vw_[bb] = vvec[col];
  }
#pragma unroll
  for (int a = 0; a < 4; ++a) {
#pragma unroll
    for (int r = 0; r < 4; ++r) {
      float s = 0.f;
#pragma unroll
      for (int bb = 0; bb < 4; ++bb)
        s += fast_tanh(acc[a][bb][r] + qv_[bb]) * vw_[bb];
      s += __shfl_xor(s, 1);
      s += __shfl_xor(s, 2);
      s += __shfl_xor(s, 4);
      s += __shfl_xor(s, 8);
      if (l15 == 0) {
        int row = row0 + wr * 64 + a * 16 + quad * 4 + r;
        atomicAdd(&score[row], s);
      }
    }
  }
}

// ---------------- K2: softmax per batch ----------------
__global__ __launch_bounds__(256) void k_softmax(const float* __restrict__ score,
                                                 float* __restrict__ attn, int N) {
  __shared__ float sm[4];
  int b = blockIdx.x, t = threadIdx.x;
  const float* s = score + (size_t)b * N;
  float m = -1e30f;
  for (int i = t; i < N; i += 256) m = fmaxf(m, s[i]);
  for (int k = 32; k; k >>= 1) m = fmaxf(m, __shfl_xor(m, k));
  if ((t & 63) == 0) sm[t >> 6] = m;
  __syncthreads();
  m = fmaxf(fmaxf(sm[0], sm[1]), fmaxf(sm[2], sm[3]));
  __syncthreads();
  float sum = 0.f;
  for (int i = t; i < N; i += 256) sum += __expf(s[i] - m);
  for (int k = 32; k; k >>= 1) sum += __shfl_xor(sum, k);
  if ((t & 63) == 0) sm[t >> 6] = sum;
  __syncthreads();
  sum = sm[0] + sm[1] + sm[2] + sm[3];
  float inv = 1.f / sum;
  for (int i = t; i < N; i += 256) attn[(size_t)b * N + i] = __expf(s[i] - m) * inv;
}

// ---------------- K3: weighted feature sum -> ctx_pre ----------------
__global__ __launch_bounds__(256) void k_wsum(const float* __restrict__ feats,
                                              const float* __restrict__ attn,
                                              float* __restrict__ ctx_pre,
                                              int N, int F, int colOff, int rowsPerChunk) {
  int b = blockIdx.x, rc = blockIdx.y, t = threadIdx.x;
  int c4 = t * 4;
  if (c4 >= F) return;
  int r0 = rc * rowsPerChunk;
  const float* fb = feats + ((size_t)b * N + r0) * F;
  const float* ab = attn + (size_t)b * N + r0;
  float4 acc = {0.f, 0.f, 0.f, 0.f};
  for (int r = 0; r < rowsPerChunk; ++r) {
    float a = ab[r];
    float4 v = *(const float4*)(fb + (size_t)r * F + c4);
    acc.x += a * v.x; acc.y += a * v.y; acc.z += a * v.z; acc.w += a * v.w;
  }
  float* dst = ctx_pre + b * 1536 + colOff + c4;
  atomicAdd(dst + 0, acc.x);
  atomicAdd(dst + 1, acc.y);
  atomicAdd(dst + 2, acc.z);
  atomicAdd(dst + 3, acc.w);
}

// ---------------- K4: ctx = ctx_pre @ W + bW ----------------
__global__ __launch_bounds__(256) void k_final(const float* __restrict__ cp,
                                               const float* __restrict__ W,
                                               const float* __restrict__ bW,
                                               float* __restrict__ out) {
  int b = blockIdx.x, oc = blockIdx.y, t = threadIdx.x;
  int o = oc * 256 + t;
  float acc = bW[o];
  const float* c = cp + b * 1536;
  for (int k = 0; k < 1536; ++k) acc += c[k] * W[k * FEAT_ + o];
  out[b * FEAT_ + o] = acc;
}

extern "C" void kernel_launch(void* const* d_in, const int* in_sizes, int n_in,
                              void* d_out, int out_size, void* d_ws, size_t ws_size,
                              hipStream_t stream) {
  const float* query = (const float*)d_in[0];
  const float* vf    = (const float*)d_in[1];
  const float* sf    = (const float*)d_in[2];
  const float* pat   = (const float*)d_in[3];
  const float* W1v   = (const float*)d_in[4];
  const float* W2v   = (const float*)d_in[5];
  const float* vv    = (const float*)d_in[6];
  const float* W3    = (const float*)d_in[7];
  const float* b3    = (const float*)d_in[8];
  const float* W1s   = (const float*)d_in[9];
  const float* W2s   = (const float*)d_in[10];
  const float* vs    = (const float*)d_in[11];
  const float* W     = (const float*)d_in[12];
  const float* bW    = (const float*)d_in[13];
  float* out = (float*)d_out;

  char* ws = (char*)d_ws;
  float* scores_v = (float*)(ws);                 // 65536 f
  float* scores_s = (float*)(ws + 262144);        // 16384 f
  float* ctx_pre  = (float*)(ws + 327680);        // 49152 f
  float* pm   = (float*)(ws + 524288);
  float* qpv  = (float*)(ws + 589824);
  float* qps  = (float*)(ws + 655360);
  unsigned short* Wtv = (unsigned short*)(ws + 720896);            // 1 MB
  unsigned short* Wts = (unsigned short*)(ws + 720896 + 1048576);  // 0.5 MB
  unsigned short* Av  = (unsigned short*)(ws + 4194304);           // 128 MiB
  unsigned short* Asm = (unsigned short*)(ws + 4194304 + 134217728); // 16 MiB
  const size_t NEED = 4194304ull + 134217728ull + 16777216ull;

  hipMemsetAsync(d_ws, 0, 524288, stream);

  k_pmean<<<32, 256, 0, stream>>>(pat, pm);
  k_qp<<<64, 256, 0, stream>>>(query, pm, W1v, W1s, W3, b3, qpv, qps);
  k_swz<<<(FEAT_ * ATT_) / 256, 256, 0, stream>>>(W2v, Wtv, FEAT_ * ATT_);
  k_swz<<<(SEM_ * ATT_) / 256, 256, 0, stream>>>(W2s, Wts, SEM_ * ATT_);

  if (ws_size >= NEED) {
    k_cvtA<<<dim3((B_ * NV_) / 128, FEAT_ / 32), 256, 0, stream>>>(vf, Av, FEAT_);
    k_cvtA<<<dim3((B_ * NS_) / 128, SEM_ / 32), 256, 0, stream>>>(sf, Asm, SEM_);
    k_scores_bf16<<<dim3(4, (B_ * NV_) / 128), 256, 0, stream>>>(Av, Wtv, qpv, vv, scores_v, FEAT_, NV_);
    k_scores_bf16<<<dim3(4, (B_ * NS_) / 128), 256, 0, stream>>>(Asm, Wts, qps, vs, scores_s, SEM_, NS_);
  } else {
    k_scores_f32<<<dim3((B_ * NV_) / 128, 4), 256, 0, stream>>>(vf, Wtv, qpv, vv, scores_v, FEAT_, NV_);
    k_scores_f32<<<dim3((B_ * NS_) / 128, 4), 256, 0, stream>>>(sf, Wts, qps, vs, scores_s, SEM_, NS_);
  }

  float* v_attn = out + B_ * FEAT_;
  float* s_attn = out + B_ * FEAT_ + B_ * NV_;
  k_softmax<<<B_, 256, 0, stream>>>(scores_v, v_attn, NV_);
  k_softmax<<<B_, 256, 0, stream>>>(scores_s, s_attn, NS_);

  k_wsum<<<dim3(B_, 8), 256, 0, stream>>>(vf, v_attn, ctx_pre, NV_, FEAT_, 0, 256);
  k_wsum<<<dim3(B_, 2), 256, 0, stream>>>(sf, s_attn, ctx_pre, NS_, SEM_, 1024, 256);

  k_final<<<dim3(B_, 4), 256, 0, stream>>>(ctx_pre, W, bW, out);
}

// Round 3
// 778.083 us; speedup vs baseline: 1.2575x; 1.2575x over previous
//
#include <hip/hip_runtime.h>

typedef float f32x4 __attribute__((ext_vector_type(4)));
typedef short short8 __attribute__((ext_vector_type(8)));

// Problem constants
#define B_    32
#define NV_   2048
#define NS_   512
#define L_    64
#define FEAT_ 1024
#define SEM_  512
#define HID_  512
#define ATT_  512
#define DM_   512

__device__ __forceinline__ unsigned int f2bf_pk(float lo, float hi) {
  unsigned int ul = (__float_as_uint(lo) + 0x8000u) >> 16;
  unsigned int uh = (__float_as_uint(hi) + 0x8000u) & 0xffff0000u;
  return uh | ul;
}

__device__ __forceinline__ unsigned short f2bf(float f) {
  return (unsigned short)((__float_as_uint(f) + 0x8000u) >> 16);
}

__device__ __forceinline__ float bflo(unsigned int u) { return __uint_as_float(u << 16); }
__device__ __forceinline__ float bfhi(unsigned int u) { return __uint_as_float(u & 0xffff0000u); }

__device__ __forceinline__ float fast_tanh(float x) {
  float e = __expf(2.f * x);
  return 1.f - 2.f * __builtin_amdgcn_rcpf(e + 1.f);
}

// async global->LDS, 16 B per lane. lds ptr must be wave-uniform; lane i lands at lds + i*16.
__device__ __forceinline__ void gll16(const void* g, void* l) {
  __builtin_amdgcn_global_load_lds(
      (const __attribute__((address_space(1))) unsigned int*)g,
      (__attribute__((address_space(3))) unsigned int*)l, 16, 0, 0);
}

// ---------------- K0a: patient mean ----------------
__global__ __launch_bounds__(256) void k_pmean(const float* __restrict__ pat,
                                               float* __restrict__ pm) {
  int b = blockIdx.x, t = threadIdx.x;
  for (int d = t; d < DM_; d += 256) {
    float s = 0.f;
    for (int l = 0; l < L_; ++l) s += pat[(b * L_ + l) * DM_ + d];
    pm[b * DM_ + d] = s * (1.f / 64.f);
  }
}

// ---------------- K0b: qpv/qps ----------------
__global__ __launch_bounds__(256) void k_qp(const float* __restrict__ query,
                                            const float* __restrict__ pm,
                                            const float* __restrict__ W1v,
                                            const float* __restrict__ W1s,
                                            const float* __restrict__ W3,
                                            const float* __restrict__ b3,
                                            float* __restrict__ qpv,
                                            float* __restrict__ qps) {
  int idx = blockIdx.x * 256 + threadIdx.x;
  int b = idx >> 9, a = idx & 511;
  float pi = b3[a];
  for (int d = 0; d < DM_; ++d) pi += pm[b * DM_ + d] * W3[d * ATT_ + a];
  float qv = 0.f, qs = 0.f;
  for (int h = 0; h < HID_; ++h) {
    float q = query[b * HID_ + h];
    qv += q * W1v[h * ATT_ + a];
    qs += q * W1s[h * ATT_ + a];
  }
  qpv[idx] = qv + pi;
  qps[idx] = qs + pi;
}

// ---------------- K0c: swizzle W2 (K x 512 fp32) -> bf16 B-fragment order ----------
__global__ __launch_bounds__(256) void k_swz(const float* __restrict__ W2,
                                             unsigned short* __restrict__ out,
                                             int total) {
  int idx = blockIdx.x * 256 + threadIdx.x;
  if (idx >= total) return;
  int k = idx >> 9, c = idx & 511;
  int kc = k >> 5, kr = k & 31, q = kr >> 3, j = kr & 7;
  int cb = c >> 4, n = c & 15;
  out[(kc * 32 + cb) * 512 + q * 128 + n * 8 + j] = f2bf(W2[idx]);
}

// ---------------- K0d: X fp32 row-major -> bf16 swizzled A-tile image -------
// per (rt,kc) 8KB block [rb<8][q<4][m<16][j<8]; row=rt*128+rb*16+m, k=kc*32+q*8+j
__global__ __launch_bounds__(256) void k_cvtA(const float* __restrict__ X,
                                              unsigned short* __restrict__ out,
                                              int K) {
  const int rt = blockIdx.x, kc = blockIdx.y, nkc = K >> 5;
  const int t = threadIdx.x;
  uint4* dst = (uint4*)(out + ((size_t)rt * nkc + kc) * 4096);
#pragma unroll
  for (int p = 0; p < 2; ++p) {
    int c = p * 256 + t;
    int rb = c >> 6, q = (c >> 4) & 3, m = c & 15;
    int row = rt * 128 + rb * 16 + m;
    const float4* src = (const float4*)(X + (size_t)row * K + kc * 32 + q * 8);
    float4 v0 = src[0], v1 = src[1];
    uint4 o;
    o.x = f2bf_pk(v0.x, v0.y);
    o.y = f2bf_pk(v0.z, v0.w);
    o.z = f2bf_pk(v1.x, v1.y);
    o.w = f2bf_pk(v1.z, v1.w);
    dst[c] = o;
  }
}

// ---------------- K1: fused score GEMM (bf16 pre-swizzled A and B) ----------------
__global__ __launch_bounds__(256) void k_scores_bf16(const unsigned short* __restrict__ Aswz,
                                                     const unsigned short* __restrict__ Wt,
                                                     const float* __restrict__ qp,
                                                     const float* __restrict__ vvec,
                                                     float* __restrict__ score,
                                                     int K, int rows_per_batch) {
  __shared__ __align__(16) unsigned short As[4096];
  __shared__ __align__(16) unsigned short Bs[4096];
  const int t = threadIdx.x;
  const int lane = t & 63;
  const int wave = t >> 6;
  const int wr = wave & 1, wc = wave >> 1;
  const int quad = lane >> 4, l15 = lane & 15;
  const int ct = blockIdx.x;
  const int rt = blockIdx.y;
  const int row0 = rt * 128;
  const int b = row0 / rows_per_batch;
  const int nk = K >> 5;

  char* ldsA = (char*)As + wave * 1024;
  char* ldsB = (char*)Bs + wave * 1024;
  const char* gA = (const char*)(Aswz + (size_t)rt * nk * 4096) + t * 16;
  const char* gB = (const char*)Wt + (size_t)ct * 8192 + t * 16;

  const f32x4 zero = {0.f, 0.f, 0.f, 0.f};
  f32x4 acc[4][4];
#pragma unroll
  for (int a = 0; a < 4; ++a)
#pragma unroll
    for (int bb = 0; bb < 4; ++bb) acc[a][bb] = zero;

  for (int kc = 0; kc < nk; ++kc) {
    __syncthreads();
    gll16(gA, ldsA);
    gll16(gA + 4096, ldsA + 4096);
    gll16(gB, ldsB);
    gll16(gB + 4096, ldsB + 4096);
    gA += 8192;
    gB += 32768;
    __syncthreads();
    short8 af[4], bfr[4];
#pragma unroll
    for (int a = 0; a < 4; ++a)
      af[a] = *(const short8*)(As + (wr * 4 + a) * 512 + quad * 128 + l15 * 8);
#pragma unroll
    for (int bb = 0; bb < 4; ++bb)
      bfr[bb] = *(const short8*)(Bs + (wc * 4 + bb) * 512 + quad * 128 + l15 * 8);
#pragma unroll
    for (int a = 0; a < 4; ++a)
#pragma unroll
      for (int bb = 0; bb < 4; ++bb)
        acc[a][bb] = __builtin_amdgcn_mfma_f32_16x16x32_bf16(af[a], bfr[bb], acc[a][bb], 0, 0, 0);
  }

  const int colbase = ct * 128 + wc * 64;
  float qv_[4], vw_[4];
#pragma unroll
  for (int bb = 0; bb < 4; ++bb) {
    int col = colbase + bb * 16 + l15;
    qv_[bb] = qp[b * ATT_ + col];
    vw_[bb] = vvec[col];
  }
#pragma unroll
  for (int a = 0; a < 4; ++a) {
#pragma unroll
    for (int r = 0; r < 4; ++r) {
      float s = 0.f;
#pragma unroll
      for (int bb = 0; bb < 4; ++bb)
        s += fast_tanh(acc[a][bb][r] + qv_[bb]) * vw_[bb];
      s += __shfl_xor(s, 1);
      s += __shfl_xor(s, 2);
      s += __shfl_xor(s, 4);
      s += __shfl_xor(s, 8);
      if (l15 == 0) {
        int row = row0 + wr * 64 + a * 16 + quad * 4 + r;
        atomicAdd(&score[row], s);
      }
    }
  }
}

// ---------------- K1-fallback: inline fp32->bf16 staging ----------
__global__ __launch_bounds__(256) void k_scores_f32(const float* __restrict__ X,
                                                    const unsigned short* __restrict__ Wt,
                                                    const float* __restrict__ qp,
                                                    const float* __restrict__ vvec,
                                                    float* __restrict__ score,
                                                    int K, int rows_per_batch) {
  __shared__ __align__(16) unsigned short As[4096];
  __shared__ __align__(16) unsigned short Bs[4096];
  const int t = threadIdx.x;
  const int lane = t & 63;
  const int wave = t >> 6;
  const int wr = wave & 1, wc = wave >> 1;
  const int quad = lane >> 4, l15 = lane & 15;
  const int row0 = blockIdx.x * 128;
  const int ct = blockIdx.y;
  const int b = row0 / rows_per_batch;

  const int ai_row = t >> 3;
  const int ai_k0 = (t & 7) * 4;
  const int a_q = ai_k0 >> 3;
  const int a_j0 = ai_k0 & 7;

  const f32x4 zero = {0.f, 0.f, 0.f, 0.f};
  f32x4 acc[4][4];
#pragma unroll
  for (int a = 0; a < 4; ++a)
#pragma unroll
    for (int bb = 0; bb < 4; ++bb) acc[a][bb] = zero;

  const int nk = K >> 5;
  for (int kc = 0; kc < nk; ++kc) {
    __syncthreads();
#pragma unroll
    for (int ii = 0; ii < 4; ++ii) {
      int i = ii * 32 + ai_row;
      const float4 v = *(const float4*)(X + (size_t)(row0 + i) * K + kc * 32 + ai_k0);
      uint2 h;
      h.x = f2bf_pk(v.x, v.y);
      h.y = f2bf_pk(v.z, v.w);
      int rb = i >> 4, m = i & 15;
      *(uint2*)(As + rb * 512 + a_q * 128 + m * 8 + a_j0) = h;
    }
    {
      const uint4* src = (const uint4*)(Wt + (size_t)(kc * 32 + ct * 8) * 512);
      uint4* dst = (uint4*)Bs;
      dst[t] = src[t];
      dst[t + 256] = src[t + 256];
    }
    __syncthreads();
    short8 af[4], bfr[4];
#pragma unroll
    for (int a = 0; a < 4; ++a)
      af[a] = *(const short8*)(As + (wr * 4 + a) * 512 + quad * 128 + l15 * 8);
#pragma unroll
    for (int bb = 0; bb < 4; ++bb)
      bfr[bb] = *(const short8*)(Bs + (wc * 4 + bb) * 512 + quad * 128 + l15 * 8);
#pragma unroll
    for (int a = 0; a < 4; ++a)
#pragma unroll
      for (int bb = 0; bb < 4; ++bb)
        acc[a][bb] = __builtin_amdgcn_mfma_f32_16x16x32_bf16(af[a], bfr[bb], acc[a][bb], 0, 0, 0);
  }

  const int colbase = ct * 128 + wc * 64;
  float qv_[4], vw_[4];
#pragma unroll
  for (int bb = 0; bb < 4; ++bb) {
    int col = colbase + bb * 16 + l15;
    qv_[bb] = qp[b * ATT_ + col];
    vw_[bb] = vvec[col];
  }
#pragma unroll
  for (int a = 0; a < 4; ++a) {
#pragma unroll
    for (int r = 0; r < 4; ++r) {
      float s = 0.f;
#pragma unroll
      for (int bb = 0; bb < 4; ++bb)
        s += fast_tanh(acc[a][bb][r] + qv_[bb]) * vw_[bb];
      s += __shfl_xor(s, 1);
      s += __shfl_xor(s, 2);
      s += __shfl_xor(s, 4);
      s += __shfl_xor(s, 8);
      if (l15 == 0) {
        int row = row0 + wr * 64 + a * 16 + quad * 4 + r;
        atomicAdd(&score[row], s);
      }
    }
  }
}

// ---------------- K2: softmax per batch ----------------
__global__ __launch_bounds__(256) void k_softmax(const float* __restrict__ score,
                                                 float* __restrict__ attn, int N) {
  __shared__ float sm[4];
  int b = blockIdx.x, t = threadIdx.x;
  const float* s = score + (size_t)b * N;
  float m = -1e30f;
  for (int i = t; i < N; i += 256) m = fmaxf(m, s[i]);
  for (int k = 32; k; k >>= 1) m = fmaxf(m, __shfl_xor(m, k));
  if ((t & 63) == 0) sm[t >> 6] = m;
  __syncthreads();
  m = fmaxf(fmaxf(sm[0], sm[1]), fmaxf(sm[2], sm[3]));
  __syncthreads();
  float sum = 0.f;
  for (int i = t; i < N; i += 256) sum += __expf(s[i] - m);
  for (int k = 32; k; k >>= 1) sum += __shfl_xor(sum, k);
  if ((t & 63) == 0) sm[t >> 6] = sum;
  __syncthreads();
  sum = sm[0] + sm[1] + sm[2] + sm[3];
  float inv = 1.f / sum;
  for (int i = t; i < N; i += 256) attn[(size_t)b * N + i] = __expf(s[i] - m) * inv;
}

// ---------------- K3: weighted sum from SWIZZLED bf16 features ----------------
// grid (B, nkc). wave q owns feats kc*32+q*8..+7; lanes cover 64 rows; no atomics.
__global__ __launch_bounds__(256) void k_wsum_swz(const unsigned short* __restrict__ Aswz,
                                                  const float* __restrict__ attn,
                                                  float* __restrict__ ctx_pre,
                                                  int nkc, int rtPerBatch,
                                                  int rowsPerBatch, int colOff) {
  const int b = blockIdx.x, kc = blockIdx.y;
  const int t = threadIdx.x, q = t >> 6, l = t & 63;
  const int rbl = l >> 4, m = l & 15;
  float acc[8] = {0.f, 0.f, 0.f, 0.f, 0.f, 0.f, 0.f, 0.f};
  for (int rt = 0; rt < rtPerBatch; ++rt) {
    const unsigned short* blk = Aswz + ((size_t)(b * rtPerBatch + rt) * nkc + kc) * 4096;
    const float* ab = attn + (size_t)b * rowsPerBatch + rt * 128;
#pragma unroll
    for (int p = 0; p < 2; ++p) {
      int rb = p * 4 + rbl;
      float a = ab[rb * 16 + m];
      uint4 v = *(const uint4*)(blk + rb * 512 + q * 128 + m * 8);
      acc[0] += a * bflo(v.x);
      acc[1] += a * bfhi(v.x);
      acc[2] += a * bflo(v.y);
      acc[3] += a * bfhi(v.y);
      acc[4] += a * bflo(v.z);
      acc[5] += a * bfhi(v.z);
      acc[6] += a * bflo(v.w);
      acc[7] += a * bfhi(v.w);
    }
  }
#pragma unroll
  for (int off = 1; off < 64; off <<= 1) {
#pragma unroll
    for (int j = 0; j < 8; ++j) acc[j] += __shfl_xor(acc[j], off);
  }
  if (l == 0) {
    float* dst = ctx_pre + b * 1536 + colOff + kc * 32 + q * 8;
#pragma unroll
    for (int j = 0; j < 8; ++j) dst[j] = acc[j];
  }
}

// ---------------- K3-fallback: fp32 weighted sum (atomics) ----------------
__global__ __launch_bounds__(256) void k_wsum(const float* __restrict__ feats,
                                              const float* __restrict__ attn,
                                              float* __restrict__ ctx_pre,
                                              int N, int F, int colOff, int rowsPerChunk) {
  int b = blockIdx.x, rc = blockIdx.y, t = threadIdx.x;
  int c4 = t * 4;
  if (c4 >= F) return;
  int r0 = rc * rowsPerChunk;
  const float* fb = feats + ((size_t)b * N + r0) * F;
  const float* ab = attn + (size_t)b * N + r0;
  float4 acc = {0.f, 0.f, 0.f, 0.f};
  for (int r = 0; r < rowsPerChunk; ++r) {
    float a = ab[r];
    float4 v = *(const float4*)(fb + (size_t)r * F + c4);
    acc.x += a * v.x; acc.y += a * v.y; acc.z += a * v.z; acc.w += a * v.w;
  }
  float* dst = ctx_pre + b * 1536 + colOff + c4;
  atomicAdd(dst + 0, acc.x);
  atomicAdd(dst + 1, acc.y);
  atomicAdd(dst + 2, acc.z);
  atomicAdd(dst + 3, acc.w);
}

// ---------------- K4: ctx = ctx_pre @ W + bW ----------------
__global__ __launch_bounds__(256) void k_final(const float* __restrict__ cp,
                                               const float* __restrict__ W,
                                               const float* __restrict__ bW,
                                               float* __restrict__ out) {
  int b = blockIdx.x, oc = blockIdx.y, t = threadIdx.x;
  int o = oc * 256 + t;
  float acc = bW[o];
  const float* c = cp + b * 1536;
  for (int k = 0; k < 1536; ++k) acc += c[k] * W[k * FEAT_ + o];
  out[b * FEAT_ + o] = acc;
}

extern "C" void kernel_launch(void* const* d_in, const int* in_sizes, int n_in,
                              void* d_out, int out_size, void* d_ws, size_t ws_size,
                              hipStream_t stream) {
  const float* query = (const float*)d_in[0];
  const float* vf    = (const float*)d_in[1];
  const float* sf    = (const float*)d_in[2];
  const float* pat   = (const float*)d_in[3];
  const float* W1v   = (const float*)d_in[4];
  const float* W2v   = (const float*)d_in[5];
  const float* vv    = (const float*)d_in[6];
  const float* W3    = (const float*)d_in[7];
  const float* b3    = (const float*)d_in[8];
  const float* W1s   = (const float*)d_in[9];
  const float* W2s   = (const float*)d_in[10];
  const float* vs    = (const float*)d_in[11];
  const float* W     = (const float*)d_in[12];
  const float* bW    = (const float*)d_in[13];
  float* out = (float*)d_out;

  char* ws = (char*)d_ws;
  float* scores_v = (float*)(ws);                 // [0, 262144)
  float* scores_s = (float*)(ws + 262144);        // [262144, 327680)
  float* ctx_pre  = (float*)(ws + 327680);        // 49152 f (no zeroing needed in bf16 path)
  float* pm   = (float*)(ws + 524288);
  float* qpv  = (float*)(ws + 589824);
  float* qps  = (float*)(ws + 655360);
  unsigned short* Wtv = (unsigned short*)(ws + 720896);              // 1 MB
  unsigned short* Wts = (unsigned short*)(ws + 720896 + 1048576);    // 0.5 MB
  unsigned short* Av  = (unsigned short*)(ws + 4194304);             // 128 MiB
  unsigned short* Asm = (unsigned short*)(ws + 4194304 + 134217728); // 16 MiB
  const size_t NEED = 4194304ull + 134217728ull + 16777216ull;
  const bool bf16path = (ws_size >= NEED);

  hipMemsetAsync(d_ws, 0, bf16path ? 327680 : 524288, stream);

  k_pmean<<<32, 256, 0, stream>>>(pat, pm);
  k_qp<<<64, 256, 0, stream>>>(query, pm, W1v, W1s, W3, b3, qpv, qps);
  k_swz<<<(FEAT_ * ATT_) / 256, 256, 0, stream>>>(W2v, Wtv, FEAT_ * ATT_);
  k_swz<<<(SEM_ * ATT_) / 256, 256, 0, stream>>>(W2s, Wts, SEM_ * ATT_);

  float* v_attn = out + B_ * FEAT_;
  float* s_attn = out + B_ * FEAT_ + B_ * NV_;

  if (bf16path) {
    k_cvtA<<<dim3((B_ * NV_) / 128, FEAT_ / 32), 256, 0, stream>>>(vf, Av, FEAT_);
    k_cvtA<<<dim3((B_ * NS_) / 128, SEM_ / 32), 256, 0, stream>>>(sf, Asm, SEM_);
    k_scores_bf16<<<dim3(4, (B_ * NV_) / 128), 256, 0, stream>>>(Av, Wtv, qpv, vv, scores_v, FEAT_, NV_);
    k_scores_bf16<<<dim3(4, (B_ * NS_) / 128), 256, 0, stream>>>(Asm, Wts, qps, vs, scores_s, SEM_, NS_);
    k_softmax<<<B_, 256, 0, stream>>>(scores_v, v_attn, NV_);
    k_softmax<<<B_, 256, 0, stream>>>(scores_s, s_attn, NS_);
    k_wsum_swz<<<dim3(B_, FEAT_ / 32), 256, 0, stream>>>(Av, v_attn, ctx_pre, FEAT_ / 32, NV_ / 128, NV_, 0);
    k_wsum_swz<<<dim3(B_, SEM_ / 32), 256, 0, stream>>>(Asm, s_attn, ctx_pre, SEM_ / 32, NS_ / 128, NS_, 1024);
  } else {
    k_scores_f32<<<dim3((B_ * NV_) / 128, 4), 256, 0, stream>>>(vf, Wtv, qpv, vv, scores_v, FEAT_, NV_);
    k_scores_f32<<<dim3((B_ * NS_) / 128, 4), 256, 0, stream>>>(sf, Wts, qps, vs, scores_s, SEM_, NS_);
    k_softmax<<<B_, 256, 0, stream>>>(scores_v, v_attn, NV_);
    k_softmax<<<B_, 256, 0, stream>>>(scores_s, s_attn, NS_);
    k_wsum<<<dim3(B_, 8), 256, 0, stream>>>(vf, v_attn, ctx_pre, NV_, FEAT_, 0, 256);
    k_wsum<<<dim3(B_, 2), 256, 0, stream>>>(sf, s_attn, ctx_pre, NS_, SEM_, 1024, 256);
  }

  k_final<<<dim3(B_, 4), 256, 0, stream>>>(ctx_pre, W, bW, out);
}

// Round 4
// 685.824 us; speedup vs baseline: 1.4267x; 1.1345x over previous
//
#include <hip/hip_runtime.h>

typedef float f32x4 __attribute__((ext_vector_type(4)));
typedef short short8 __attribute__((ext_vector_type(8)));

// Problem constants
#define B_    32
#define NV_   2048
#define NS_   512
#define L_    64
#define FEAT_ 1024
#define SEM_  512
#define HID_  512
#define ATT_  512
#define DM_   512

__device__ __forceinline__ unsigned int f2bf_pk(float lo, float hi) {
  unsigned int ul = (__float_as_uint(lo) + 0x8000u) >> 16;
  unsigned int uh = (__float_as_uint(hi) + 0x8000u) & 0xffff0000u;
  return uh | ul;
}

__device__ __forceinline__ unsigned short f2bf(float f) {
  return (unsigned short)((__float_as_uint(f) + 0x8000u) >> 16);
}

__device__ __forceinline__ float bflo(unsigned int u) { return __uint_as_float(u << 16); }
__device__ __forceinline__ float bfhi(unsigned int u) { return __uint_as_float(u & 0xffff0000u); }

__device__ __forceinline__ float fast_tanh(float x) {
  float e = __expf(2.f * x);
  return 1.f - 2.f * __builtin_amdgcn_rcpf(e + 1.f);
}

// ---------------- K0a: patient mean ----------------
__global__ __launch_bounds__(256) void k_pmean(const float* __restrict__ pat,
                                               float* __restrict__ pm) {
  int b = blockIdx.x, t = threadIdx.x;
  for (int d = t; d < DM_; d += 256) {
    float s = 0.f;
    for (int l = 0; l < L_; ++l) s += pat[(b * L_ + l) * DM_ + d];
    pm[b * DM_ + d] = s * (1.f / 64.f);
  }
}

// ---------------- K0b: qpv/qps ----------------
__global__ __launch_bounds__(256) void k_qp(const float* __restrict__ query,
                                            const float* __restrict__ pm,
                                            const float* __restrict__ W1v,
                                            const float* __restrict__ W1s,
                                            const float* __restrict__ W3,
                                            const float* __restrict__ b3,
                                            float* __restrict__ qpv,
                                            float* __restrict__ qps) {
  int idx = blockIdx.x * 256 + threadIdx.x;
  int b = idx >> 9, a = idx & 511;
  float pi = b3[a];
  for (int d = 0; d < DM_; ++d) pi += pm[b * DM_ + d] * W3[d * ATT_ + a];
  float qv = 0.f, qs = 0.f;
  for (int h = 0; h < HID_; ++h) {
    float q = query[b * HID_ + h];
    qv += q * W1v[h * ATT_ + a];
    qs += q * W1s[h * ATT_ + a];
  }
  qpv[idx] = qv + pi;
  qps[idx] = qs + pi;
}

// ---------------- K0c: swizzle W2 (K x 512 fp32) -> bf16 B-fragment order ----------
// out block (kc,ct): bytes [(kc*4+ct)*8192, ...): [cb<8][q<4][n<16][j<8]
__global__ __launch_bounds__(256) void k_swz(const float* __restrict__ W2,
                                             unsigned short* __restrict__ out,
                                             int total) {
  int idx = blockIdx.x * 256 + threadIdx.x;
  if (idx >= total) return;
  int k = idx >> 9, c = idx & 511;
  int kc = k >> 5, kr = k & 31, q = kr >> 3, j = kr & 7;
  int cb = c >> 4, n = c & 15;
  out[(kc * 32 + cb) * 512 + q * 128 + n * 8 + j] = f2bf(W2[idx]);
}

// ---------------- K1: fused score GEMM, single A pass + Av byproduct ----------------
// Block: 64 rows x 512 cols, 4 waves (wave w = cols w*128..+127, all 64 rows).
// A: fp32 -> bf16 inline into 4KB LDS (fragment order) + global store to Av.
// B: direct coalesced global loads from pre-swizzled Wt (L2-resident).
__global__ __launch_bounds__(256, 2) void k_scores_fused(
    const float* __restrict__ X, const unsigned short* __restrict__ Wt,
    const float* __restrict__ qp, const float* __restrict__ vvec,
    float* __restrict__ score, unsigned short* __restrict__ Av,
    int K, int rows_per_batch) {
  __shared__ __align__(16) unsigned short As[2048];  // [rb<4][q<4][m<16][j<8]
  const int t = threadIdx.x;
  const int lane = t & 63, wave = t >> 6;
  const int quad = lane >> 4, l15 = lane & 15;
  const int row0 = blockIdx.x * 64;
  const int b = row0 / rows_per_batch;
  const int nk = K >> 5;
  const int rt128 = blockIdx.x >> 1;
  const int rbOff = (blockIdx.x & 1) * 4;

  // A staging map: thread t -> row r = t>>2, k0 = (t&3)*8
  const int r = t >> 2, q_ = t & 3;
  const int arb = r >> 4, am = r & 15;
  const float* gA = X + (size_t)(row0 + r) * K + q_ * 8;
  uint4* asDst = (uint4*)(As + arb * 512 + q_ * 128 + am * 8);
  char* avBase = (char*)(Av + (size_t)rt128 * nk * 4096) +
                 (rbOff + arb) * 1024 + q_ * 256 + am * 16;

  const char* gB = (const char*)Wt + (size_t)wave * 8192 + lane * 16;

  const f32x4 zero = {0.f, 0.f, 0.f, 0.f};
  f32x4 acc[4][8];
#pragma unroll
  for (int a = 0; a < 4; ++a)
#pragma unroll
    for (int cb = 0; cb < 8; ++cb) acc[a][cb] = zero;

  for (int kc = 0; kc < nk; ++kc) {
    // B fragments: direct from global (L2-hot, 1 MB weight)
    short8 bfr[8];
    const char* gBk = gB + (size_t)kc * 32768;
#pragma unroll
    for (int cb = 0; cb < 8; ++cb)
      bfr[cb] = *(const short8*)(gBk + cb * 1024);

    __syncthreads();
    const float4 v0 = *(const float4*)(gA + kc * 32);
    const float4 v1 = *(const float4*)(gA + kc * 32 + 4);
    uint4 o;
    o.x = f2bf_pk(v0.x, v0.y);
    o.y = f2bf_pk(v0.z, v0.w);
    o.z = f2bf_pk(v1.x, v1.y);
    o.w = f2bf_pk(v1.z, v1.w);
    *asDst = o;
    *(uint4*)(avBase + (size_t)kc * 8192) = o;
    __syncthreads();

    short8 af[4];
#pragma unroll
    for (int a = 0; a < 4; ++a)
      af[a] = *(const short8*)(As + a * 512 + quad * 128 + l15 * 8);
#pragma unroll
    for (int a = 0; a < 4; ++a)
#pragma unroll
      for (int cb = 0; cb < 8; ++cb)
        acc[a][cb] = __builtin_amdgcn_mfma_f32_16x16x32_bf16(af[a], bfr[cb], acc[a][cb], 0, 0, 0);
  }

  // epilogue: per row, partial over this wave's 128 cols
  float qv_[8], vw_[8];
#pragma unroll
  for (int cb = 0; cb < 8; ++cb) {
    int col = wave * 128 + cb * 16 + l15;
    qv_[cb] = qp[b * ATT_ + col];
    vw_[cb] = vvec[col];
  }
#pragma unroll
  for (int a = 0; a < 4; ++a) {
#pragma unroll
    for (int rr = 0; rr < 4; ++rr) {
      float s = 0.f;
#pragma unroll
      for (int cb = 0; cb < 8; ++cb)
        s += fast_tanh(acc[a][cb][rr] + qv_[cb]) * vw_[cb];
      s += __shfl_xor(s, 1);
      s += __shfl_xor(s, 2);
      s += __shfl_xor(s, 4);
      s += __shfl_xor(s, 8);
      if (l15 == 0) atomicAdd(&score[row0 + a * 16 + quad * 4 + rr], s);
    }
  }
}

// ---------------- K1-fallback: inline fp32->bf16 staging, split-ct ----------
__global__ __launch_bounds__(256) void k_scores_f32(const float* __restrict__ X,
                                                    const unsigned short* __restrict__ Wt,
                                                    const float* __restrict__ qp,
                                                    const float* __restrict__ vvec,
                                                    float* __restrict__ score,
                                                    int K, int rows_per_batch) {
  __shared__ __align__(16) unsigned short As[4096];
  __shared__ __align__(16) unsigned short Bs[4096];
  const int t = threadIdx.x;
  const int lane = t & 63;
  const int wave = t >> 6;
  const int wr = wave & 1, wc = wave >> 1;
  const int quad = lane >> 4, l15 = lane & 15;
  const int row0 = blockIdx.x * 128;
  const int ct = blockIdx.y;
  const int b = row0 / rows_per_batch;

  const int ai_row = t >> 3;
  const int ai_k0 = (t & 7) * 4;
  const int a_q = ai_k0 >> 3;
  const int a_j0 = ai_k0 & 7;

  const f32x4 zero = {0.f, 0.f, 0.f, 0.f};
  f32x4 acc[4][4];
#pragma unroll
  for (int a = 0; a < 4; ++a)
#pragma unroll
    for (int bb = 0; bb < 4; ++bb) acc[a][bb] = zero;

  const int nk = K >> 5;
  for (int kc = 0; kc < nk; ++kc) {
    __syncthreads();
#pragma unroll
    for (int ii = 0; ii < 4; ++ii) {
      int i = ii * 32 + ai_row;
      const float4 v = *(const float4*)(X + (size_t)(row0 + i) * K + kc * 32 + ai_k0);
      uint2 h;
      h.x = f2bf_pk(v.x, v.y);
      h.y = f2bf_pk(v.z, v.w);
      int rb = i >> 4, m = i & 15;
      *(uint2*)(As + rb * 512 + a_q * 128 + m * 8 + a_j0) = h;
    }
    {
      const uint4* src = (const uint4*)(Wt + (size_t)(kc * 32 + ct * 8) * 512);
      uint4* dst = (uint4*)Bs;
      dst[t] = src[t];
      dst[t + 256] = src[t + 256];
    }
    __syncthreads();
    short8 af[4], bfr[4];
#pragma unroll
    for (int a = 0; a < 4; ++a)
      af[a] = *(const short8*)(As + (wr * 4 + a) * 512 + quad * 128 + l15 * 8);
#pragma unroll
    for (int bb = 0; bb < 4; ++bb)
      bfr[bb] = *(const short8*)(Bs + (wc * 4 + bb) * 512 + quad * 128 + l15 * 8);
#pragma unroll
    for (int a = 0; a < 4; ++a)
#pragma unroll
      for (int bb = 0; bb < 4; ++bb)
        acc[a][bb] = __builtin_amdgcn_mfma_f32_16x16x32_bf16(af[a], bfr[bb], acc[a][bb], 0, 0, 0);
  }

  const int colbase = ct * 128 + wc * 64;
  float qv_[4], vw_[4];
#pragma unroll
  for (int bb = 0; bb < 4; ++bb) {
    int col = colbase + bb * 16 + l15;
    qv_[bb] = qp[b * ATT_ + col];
    vw_[bb] = vvec[col];
  }
#pragma unroll
  for (int a = 0; a < 4; ++a) {
#pragma unroll
    for (int r = 0; r < 4; ++r) {
      float s = 0.f;
#pragma unroll
      for (int bb = 0; bb < 4; ++bb)
        s += fast_tanh(acc[a][bb][r] + qv_[bb]) * vw_[bb];
      s += __shfl_xor(s, 1);
      s += __shfl_xor(s, 2);
      s += __shfl_xor(s, 4);
      s += __shfl_xor(s, 8);
      if (l15 == 0) {
        int row = row0 + wr * 64 + a * 16 + quad * 4 + r;
        atomicAdd(&score[row], s);
      }
    }
  }
}

// ---------------- K2: softmax per batch ----------------
__global__ __launch_bounds__(256) void k_softmax(const float* __restrict__ score,
                                                 float* __restrict__ attn, int N) {
  __shared__ float sm[4];
  int b = blockIdx.x, t = threadIdx.x;
  const float* s = score + (size_t)b * N;
  float m = -1e30f;
  for (int i = t; i < N; i += 256) m = fmaxf(m, s[i]);
  for (int k = 32; k; k >>= 1) m = fmaxf(m, __shfl_xor(m, k));
  if ((t & 63) == 0) sm[t >> 6] = m;
  __syncthreads();
  m = fmaxf(fmaxf(sm[0], sm[1]), fmaxf(sm[2], sm[3]));
  __syncthreads();
  float sum = 0.f;
  for (int i = t; i < N; i += 256) sum += __expf(s[i] - m);
  for (int k = 32; k; k >>= 1) sum += __shfl_xor(sum, k);
  if ((t & 63) == 0) sm[t >> 6] = sum;
  __syncthreads();
  sum = sm[0] + sm[1] + sm[2] + sm[3];
  float inv = 1.f / sum;
  for (int i = t; i < N; i += 256) attn[(size_t)b * N + i] = __expf(s[i] - m) * inv;
}

// ---------------- K3: weighted sum from SWIZZLED bf16 features ----------------
__global__ __launch_bounds__(256) void k_wsum_swz(const unsigned short* __restrict__ Aswz,
                                                  const float* __restrict__ attn,
                                                  float* __restrict__ ctx_pre,
                                                  int nkc, int rtPerBatch,
                                                  int rowsPerBatch, int colOff) {
  const int b = blockIdx.x, kc = blockIdx.y;
  const int t = threadIdx.x, q = t >> 6, l = t & 63;
  const int rbl = l >> 4, m = l & 15;
  float acc[8] = {0.f, 0.f, 0.f, 0.f, 0.f, 0.f, 0.f, 0.f};
  for (int rt = 0; rt < rtPerBatch; ++rt) {
    const unsigned short* blk = Aswz + ((size_t)(b * rtPerBatch + rt) * nkc + kc) * 4096;
    const float* ab = attn + (size_t)b * rowsPerBatch + rt * 128;
#pragma unroll
    for (int p = 0; p < 2; ++p) {
      int rb = p * 4 + rbl;
      float a = ab[rb * 16 + m];
      uint4 v = *(const uint4*)(blk + rb * 512 + q * 128 + m * 8);
      acc[0] += a * bflo(v.x);
      acc[1] += a * bfhi(v.x);
      acc[2] += a * bflo(v.y);
      acc[3] += a * bfhi(v.y);
      acc[4] += a * bflo(v.z);
      acc[5] += a * bfhi(v.z);
      acc[6] += a * bflo(v.w);
      acc[7] += a * bfhi(v.w);
    }
  }
#pragma unroll
  for (int off = 1; off < 64; off <<= 1) {
#pragma unroll
    for (int j = 0; j < 8; ++j) acc[j] += __shfl_xor(acc[j], off);
  }
  if (l == 0) {
    float* dst = ctx_pre + b * 1536 + colOff + kc * 32 + q * 8;
#pragma unroll
    for (int j = 0; j < 8; ++j) dst[j] = acc[j];
  }
}

// ---------------- K3-fallback: fp32 weighted sum (atomics) ----------------
__global__ __launch_bounds__(256) void k_wsum(const float* __restrict__ feats,
                                              const float* __restrict__ attn,
                                              float* __restrict__ ctx_pre,
                                              int N, int F, int colOff, int rowsPerChunk) {
  int b = blockIdx.x, rc = blockIdx.y, t = threadIdx.x;
  int c4 = t * 4;
  if (c4 >= F) return;
  int r0 = rc * rowsPerChunk;
  const float* fb = feats + ((size_t)b * N + r0) * F;
  const float* ab = attn + (size_t)b * N + r0;
  float4 acc = {0.f, 0.f, 0.f, 0.f};
  for (int r = 0; r < rowsPerChunk; ++r) {
    float a = ab[r];
    float4 v = *(const float4*)(fb + (size_t)r * F + c4);
    acc.x += a * v.x; acc.y += a * v.y; acc.z += a * v.z; acc.w += a * v.w;
  }
  float* dst = ctx_pre + b * 1536 + colOff + c4;
  atomicAdd(dst + 0, acc.x);
  atomicAdd(dst + 1, acc.y);
  atomicAdd(dst + 2, acc.z);
  atomicAdd(dst + 3, acc.w);
}

// ---------------- K4: ctx = ctx_pre @ W + bW ----------------
__global__ __launch_bounds__(256) void k_final(const float* __restrict__ cp,
                                               const float* __restrict__ W,
                                               const float* __restrict__ bW,
                                               float* __restrict__ out) {
  int b = blockIdx.x, oc = blockIdx.y, t = threadIdx.x;
  int o = oc * 256 + t;
  float acc = bW[o];
  const float* c = cp + b * 1536;
  for (int k = 0; k < 1536; ++k) acc += c[k] * W[k * FEAT_ + o];
  out[b * FEAT_ + o] = acc;
}

extern "C" void kernel_launch(void* const* d_in, const int* in_sizes, int n_in,
                              void* d_out, int out_size, void* d_ws, size_t ws_size,
                              hipStream_t stream) {
  const float* query = (const float*)d_in[0];
  const float* vf    = (const float*)d_in[1];
  const float* sf    = (const float*)d_in[2];
  const float* pat   = (const float*)d_in[3];
  const float* W1v   = (const float*)d_in[4];
  const float* W2v   = (const float*)d_in[5];
  const float* vv    = (const float*)d_in[6];
  const float* W3    = (const float*)d_in[7];
  const float* b3    = (const float*)d_in[8];
  const float* W1s   = (const float*)d_in[9];
  const float* W2s   = (const float*)d_in[10];
  const float* vs    = (const float*)d_in[11];
  const float* W     = (const float*)d_in[12];
  const float* bW    = (const float*)d_in[13];
  float* out = (float*)d_out;

  char* ws = (char*)d_ws;
  float* scores_v = (float*)(ws);                 // [0, 262144)
  float* scores_s = (float*)(ws + 262144);        // [262144, 327680)
  float* ctx_pre  = (float*)(ws + 327680);
  float* pm   = (float*)(ws + 524288);
  float* qpv  = (float*)(ws + 589824);
  float* qps  = (float*)(ws + 655360);
  unsigned short* Wtv = (unsigned short*)(ws + 720896);              // 1 MB
  unsigned short* Wts = (unsigned short*)(ws + 720896 + 1048576);    // 0.5 MB
  unsigned short* Av  = (unsigned short*)(ws + 4194304);             // 128 MiB
  unsigned short* Asm = (unsigned short*)(ws + 4194304 + 134217728); // 16 MiB
  const size_t NEED = 4194304ull + 134217728ull + 16777216ull;
  const bool bf16path = (ws_size >= NEED);

  hipMemsetAsync(d_ws, 0, bf16path ? 327680 : 524288, stream);

  k_pmean<<<32, 256, 0, stream>>>(pat, pm);
  k_qp<<<64, 256, 0, stream>>>(query, pm, W1v, W1s, W3, b3, qpv, qps);
  k_swz<<<(FEAT_ * ATT_) / 256, 256, 0, stream>>>(W2v, Wtv, FEAT_ * ATT_);
  k_swz<<<(SEM_ * ATT_) / 256, 256, 0, stream>>>(W2s, Wts, SEM_ * ATT_);

  float* v_attn = out + B_ * FEAT_;
  float* s_attn = out + B_ * FEAT_ + B_ * NV_;

  if (bf16path) {
    k_scores_fused<<<(B_ * NV_) / 64, 256, 0, stream>>>(vf, Wtv, qpv, vv, scores_v, Av, FEAT_, NV_);
    k_scores_fused<<<(B_ * NS_) / 64, 256, 0, stream>>>(sf, Wts, qps, vs, scores_s, Asm, SEM_, NS_);
    k_softmax<<<B_, 256, 0, stream>>>(scores_v, v_attn, NV_);
    k_softmax<<<B_, 256, 0, stream>>>(scores_s, s_attn, NS_);
    k_wsum_swz<<<dim3(B_, FEAT_ / 32), 256, 0, stream>>>(Av, v_attn, ctx_pre, FEAT_ / 32, NV_ / 128, NV_, 0);
    k_wsum_swz<<<dim3(B_, SEM_ / 32), 256, 0, stream>>>(Asm, s_attn, ctx_pre, SEM_ / 32, NS_ / 128, NS_, 1024);
  } else {
    k_scores_f32<<<dim3((B_ * NV_) / 128, 4), 256, 0, stream>>>(vf, Wtv, qpv, vv, scores_v, FEAT_, NV_);
    k_scores_f32<<<dim3((B_ * NS_) / 128, 4), 256, 0, stream>>>(sf, Wts, qps, vs, scores_s, SEM_, NS_);
    k_softmax<<<B_, 256, 0, stream>>>(scores_v, v_attn, NV_);
    k_softmax<<<B_, 256, 0, stream>>>(scores_s, s_attn, NS_);
    k_wsum<<<dim3(B_, 8), 256, 0, stream>>>(vf, v_attn, ctx_pre, NV_, FEAT_, 0, 256);
    k_wsum<<<dim3(B_, 2), 256, 0, stream>>>(sf, s_attn, ctx_pre, NS_, SEM_, 1024, 256);
  }

  k_final<<<dim3(B_, 4), 256, 0, stream>>>(ctx_pre, W, bW, out);
}